// Round 1
// baseline (408.727 us; speedup 1.0000x reference)
//
#include <hip/hip_runtime.h>
#include <hip/hip_bf16.h>

#define TTOK 4096
#define DIM  1024
#define HID  2048
#define ODIM 1024
#define NE   8

typedef __attribute__((ext_vector_type(8))) short  short8;
typedef __attribute__((ext_vector_type(4))) float  f32x4;
typedef __attribute__((ext_vector_type(8))) unsigned short ushort8;
typedef __attribute__((ext_vector_type(4))) unsigned short ushort4v;

__device__ __forceinline__ unsigned short f2bf(float f){
  unsigned u = __float_as_uint(f);
  u += 0x7fffu + ((u >> 16) & 1u);
  return (unsigned short)(u >> 16);
}

__device__ __forceinline__ void gld16(const void* g, void* l){
  __builtin_amdgcn_global_load_lds(
      (const __attribute__((address_space(1))) unsigned int*)g,
      (__attribute__((address_space(3))) unsigned int*)l, 16, 0, 0);
}

// ---------------- router: logits(f32) -> top2 + weights, x -> bf16 ----------
__global__ __launch_bounds__(256) void router_kernel(
    const float* __restrict__ x, const float* __restrict__ rw,
    const float* __restrict__ rb, unsigned short* __restrict__ xbf,
    int2* __restrict__ toke, float2* __restrict__ tokw, int* __restrict__ counts)
{
  int tok  = (blockIdx.x * blockDim.x + threadIdx.x) >> 6;
  int lane = threadIdx.x & 63;
  const float4* xr = (const float4*)(x + (size_t)tok * DIM + lane * 16);
  float xv[16];
#pragma unroll
  for (int q = 0; q < 4; q++){
    float4 v = xr[q];
    xv[q*4+0]=v.x; xv[q*4+1]=v.y; xv[q*4+2]=v.z; xv[q*4+3]=v.w;
  }
  ushort8 u0, u1;
#pragma unroll
  for (int j = 0; j < 8; j++){ u0[j] = f2bf(xv[j]); u1[j] = f2bf(xv[8+j]); }
  ushort8* xo = (ushort8*)(xbf + (size_t)tok * DIM + lane * 16);
  xo[0] = u0; xo[1] = u1;

  float lg[NE];
#pragma unroll
  for (int e = 0; e < NE; e++){
    const float4* wr4 = (const float4*)(rw + (size_t)e * DIM + lane * 16);
    float s = 0.f;
#pragma unroll
    for (int q = 0; q < 4; q++){
      float4 wv = wr4[q];
      s += xv[q*4+0]*wv.x + xv[q*4+1]*wv.y + xv[q*4+2]*wv.z + xv[q*4+3]*wv.w;
    }
    lg[e] = s;
  }
#pragma unroll
  for (int e = 0; e < NE; e++)
    for (int s = 1; s < 64; s <<= 1) lg[e] += __shfl_xor(lg[e], s, 64);

  if (lane == 0){
#pragma unroll
    for (int e = 0; e < NE; e++) lg[e] += rb[e];
    int e0 = 0; float l0 = lg[0];
    for (int e = 1; e < NE; e++) if (lg[e] > l0){ l0 = lg[e]; e0 = e; }
    int e1 = -1; float l1 = -1e30f;
    for (int e = 0; e < NE; e++) if (e != e0 && lg[e] > l1){ l1 = lg[e]; e1 = e; }
    float w0 = 1.f / (1.f + __expf(l1 - l0));
    float w1 = 1.f / (1.f + __expf(l0 - l1));
    toke[tok] = make_int2(e0, e1);
    tokw[tok] = make_float2(w0, w1);
    atomicAdd(counts + e0, 1);
    atomicAdd(counts + e1, 1);
  }
}

__global__ void prefix_kernel(const int* __restrict__ counts, int* __restrict__ offs){
  if (threadIdx.x == 0){
    int a = 0;
    for (int e = 0; e < NE; e++){ offs[e] = a; a += counts[e]; }
    offs[NE] = a;
  }
}

__global__ __launch_bounds__(256) void scatter_kernel(
    const int2* __restrict__ toke, const float2* __restrict__ tokw,
    const int* __restrict__ offs, int* __restrict__ cursor,
    int* __restrict__ tlist, float* __restrict__ wlist, int* __restrict__ slist)
{
  int t = blockIdx.x * 256 + threadIdx.x;
  if (t >= TTOK) return;
  int2  e = toke[t];
  float2 w = tokw[t];
  int p0 = atomicAdd(cursor + e.x, 1);
  int i0 = offs[e.x] + p0;
  tlist[i0] = t; wlist[i0] = w.x; slist[i0] = 0;
  int p1 = atomicAdd(cursor + e.y, 1);
  int i1 = offs[e.y] + p1;
  tlist[i1] = t; wlist[i1] = w.y; slist[i1] = 1;
}

// ------- transpose+convert: in [E][R][C] f32 -> out [E][C][R] bf16 ----------
__global__ __launch_bounds__(256) void transpose_cvt(
    const float* __restrict__ in, unsigned short* __restrict__ out, int R, int C)
{
  __shared__ float tile[64][65];
  int e = blockIdx.z;
  const float* src = in + (size_t)e * R * C + (size_t)(blockIdx.y * 64) * C + blockIdx.x * 64;
  int t  = threadIdx.x;
  int r0 = t >> 4, c4 = (t & 15) * 4;
#pragma unroll
  for (int it = 0; it < 4; it++){
    float4 v = *(const float4*)(src + (size_t)(r0 + it * 16) * C + c4);
    tile[r0 + it*16][c4+0] = v.x; tile[r0 + it*16][c4+1] = v.y;
    tile[r0 + it*16][c4+2] = v.z; tile[r0 + it*16][c4+3] = v.w;
  }
  __syncthreads();
  unsigned short* dst = out + (size_t)e * C * R + (size_t)(blockIdx.x * 64) * R + blockIdx.y * 64;
#pragma unroll
  for (int it = 0; it < 4; it++){
    int oc = r0 + it * 16;
    ushort4v u;
#pragma unroll
    for (int j = 0; j < 4; j++) u[j] = f2bf(tile[c4 + j][oc]);
    *(ushort4v*)(dst + (size_t)oc * R + c4) = u;
  }
}

// ---------------- stage 1: h=X@W1, g=X@W3, a = silu(h)*g  (bf16) ------------
__global__ __launch_bounds__(256,2) void ffn1_kernel(
    const unsigned short* __restrict__ xbf,
    const unsigned short* __restrict__ w1t,
    const unsigned short* __restrict__ w3t,
    unsigned short* __restrict__ abuf,
    const int* __restrict__ counts, const int* __restrict__ offs,
    const int* __restrict__ tlist)
{
  const int e = blockIdx.z, rt = blockIdx.y, ct = blockIdx.x;
  const int cnt = counts[e];
  const int rbase = rt * 128;
  if (rbase >= cnt) return;
  const int off = offs[e];
  const int rows_left = cnt - rbase;
  const int t = threadIdx.x;
  const int lane = t & 63, w = t >> 6;
  const int wr = w >> 1, wc = w & 1;

  __shared__ __align__(16) unsigned short As [128 * 32];
  __shared__ __align__(16) unsigned short B1s[128 * 32];
  __shared__ __align__(16) unsigned short B3s[128 * 32];

  int ar0 = t >> 2, ar1 = 64 + (t >> 2);
  int part = t & 3;
  int ra0 = ar0 < rows_left ? ar0 : rows_left - 1;
  int ra1 = ar1 < rows_left ? ar1 : rows_left - 1;
  int tok0 = tlist[off + rbase + ra0];
  int tok1 = tlist[off + rbase + ra1];
  const char* sA0  = (const char*)xbf + ((size_t)tok0 * DIM) * 2 + part * 16;
  const char* sA1  = (const char*)xbf + ((size_t)tok1 * DIM) * 2 + part * 16;
  const char* sB10 = (const char*)w1t + (((size_t)e * HID + ct * 128 + ar0) * DIM) * 2 + part * 16;
  const char* sB11 = (const char*)w1t + (((size_t)e * HID + ct * 128 + ar1) * DIM) * 2 + part * 16;
  const char* sB30 = (const char*)w3t + (((size_t)e * HID + ct * 128 + ar0) * DIM) * 2 + part * 16;
  const char* sB31 = (const char*)w3t + (((size_t)e * HID + ct * 128 + ar1) * DIM) * 2 + part * 16;
  char* dA0  = (char*)As  + w * 1024;  char* dA1  = (char*)As  + 4096 + w * 1024;
  char* dB10 = (char*)B1s + w * 1024;  char* dB11 = (char*)B1s + 4096 + w * 1024;
  char* dB30 = (char*)B3s + w * 1024;  char* dB31 = (char*)B3s + 4096 + w * 1024;

  const unsigned short *ap[4], *b1p[4], *b3p[4];
#pragma unroll
  for (int i = 0; i < 4; i++){
    int am = wr * 64 + i * 16 + (lane & 15);
    int bn = wc * 64 + i * 16 + (lane & 15);
    ap[i]  = As  + am * 32 + (lane >> 4) * 8;
    b1p[i] = B1s + bn * 32 + (lane >> 4) * 8;
    b3p[i] = B3s + bn * 32 + (lane >> 4) * 8;
  }

  f32x4 acch[4][4], accg[4][4];
#pragma unroll
  for (int i = 0; i < 4; i++)
#pragma unroll
    for (int j = 0; j < 4; j++){
      acch[i][j] = (f32x4){0.f,0.f,0.f,0.f};
      accg[i][j] = (f32x4){0.f,0.f,0.f,0.f};
    }

  for (int kt = 0; kt < DIM / 32; ++kt){
    gld16(sA0,  dA0);  gld16(sA1,  dA1);
    gld16(sB10, dB10); gld16(sB11, dB11);
    gld16(sB30, dB30); gld16(sB31, dB31);
    sA0 += 64; sA1 += 64; sB10 += 64; sB11 += 64; sB30 += 64; sB31 += 64;
    __syncthreads();
    short8 a[4], b1[4], b3[4];
#pragma unroll
    for (int i = 0; i < 4; i++){
      a[i]  = *(const short8*)ap[i];
      b1[i] = *(const short8*)b1p[i];
      b3[i] = *(const short8*)b3p[i];
    }
#pragma unroll
    for (int mi = 0; mi < 4; mi++)
#pragma unroll
      for (int ni = 0; ni < 4; ni++){
        acch[mi][ni] = __builtin_amdgcn_mfma_f32_16x16x32_bf16(a[mi], b1[ni], acch[mi][ni], 0, 0, 0);
        accg[mi][ni] = __builtin_amdgcn_mfma_f32_16x16x32_bf16(a[mi], b3[ni], accg[mi][ni], 0, 0, 0);
      }
    __syncthreads();
  }

#pragma unroll
  for (int mi = 0; mi < 4; mi++)
#pragma unroll
    for (int r = 0; r < 4; r++){
      int row_local = wr * 64 + mi * 16 + ((lane >> 4) << 2) + r;
      if (row_local < rows_left){
        size_t pair = (size_t)(off + rbase + row_local);
        unsigned short* arow = abuf + pair * HID + ct * 128 + wc * 64 + (lane & 15);
#pragma unroll
        for (int ni = 0; ni < 4; ni++){
          float h = acch[mi][ni][r], g = accg[mi][ni][r];
          float sv = h / (1.f + __expf(-h));
          arow[ni * 16] = f2bf(sv * g);
        }
      }
    }
}

// ---------------- stage 2: eo = A @ W2, scaled scatter into sel -------------
__global__ __launch_bounds__(256,2) void ffn2_kernel(
    const unsigned short* __restrict__ abuf,
    const unsigned short* __restrict__ w2t,
    float* __restrict__ sel,
    const int* __restrict__ counts, const int* __restrict__ offs,
    const int* __restrict__ tlist, const float* __restrict__ wlist,
    const int* __restrict__ slist)
{
  const int e = blockIdx.z, rt = blockIdx.y, ct = blockIdx.x;
  const int cnt = counts[e];
  const int rbase = rt * 128;
  if (rbase >= cnt) return;
  const int off = offs[e];
  const int rows_left = cnt - rbase;
  const int t = threadIdx.x;
  const int lane = t & 63, w = t >> 6;
  const int wr = w >> 1, wc = w & 1;

  __shared__ __align__(16) unsigned short As[128 * 32];
  __shared__ __align__(16) unsigned short Bs[128 * 32];

  int ar0 = t >> 2, ar1 = 64 + (t >> 2);
  int part = t & 3;
  int ra0 = ar0 < rows_left ? ar0 : rows_left - 1;
  int ra1 = ar1 < rows_left ? ar1 : rows_left - 1;
  const char* sA0 = (const char*)abuf + ((size_t)(off + rbase + ra0) * HID) * 2 + part * 16;
  const char* sA1 = (const char*)abuf + ((size_t)(off + rbase + ra1) * HID) * 2 + part * 16;
  const char* sB0 = (const char*)w2t + (((size_t)e * ODIM + ct * 128 + ar0) * HID) * 2 + part * 16;
  const char* sB1 = (const char*)w2t + (((size_t)e * ODIM + ct * 128 + ar1) * HID) * 2 + part * 16;
  char* dA0 = (char*)As + w * 1024;  char* dA1 = (char*)As + 4096 + w * 1024;
  char* dB0 = (char*)Bs + w * 1024;  char* dB1 = (char*)Bs + 4096 + w * 1024;

  const unsigned short *ap[4], *bp[4];
#pragma unroll
  for (int i = 0; i < 4; i++){
    int am = wr * 64 + i * 16 + (lane & 15);
    int bn = wc * 64 + i * 16 + (lane & 15);
    ap[i] = As + am * 32 + (lane >> 4) * 8;
    bp[i] = Bs + bn * 32 + (lane >> 4) * 8;
  }

  f32x4 acc[4][4];
#pragma unroll
  for (int i = 0; i < 4; i++)
#pragma unroll
    for (int j = 0; j < 4; j++) acc[i][j] = (f32x4){0.f,0.f,0.f,0.f};

  for (int kt = 0; kt < HID / 32; ++kt){
    gld16(sA0, dA0); gld16(sA1, dA1);
    gld16(sB0, dB0); gld16(sB1, dB1);
    sA0 += 64; sA1 += 64; sB0 += 64; sB1 += 64;
    __syncthreads();
    short8 a[4], b[4];
#pragma unroll
    for (int i = 0; i < 4; i++){
      a[i] = *(const short8*)ap[i];
      b[i] = *(const short8*)bp[i];
    }
#pragma unroll
    for (int mi = 0; mi < 4; mi++)
#pragma unroll
      for (int ni = 0; ni < 4; ni++)
        acc[mi][ni] = __builtin_amdgcn_mfma_f32_16x16x32_bf16(a[mi], b[ni], acc[mi][ni], 0, 0, 0);
    __syncthreads();
  }

#pragma unroll
  for (int mi = 0; mi < 4; mi++)
#pragma unroll
    for (int r = 0; r < 4; r++){
      int row_local = wr * 64 + mi * 16 + ((lane >> 4) << 2) + r;
      if (row_local < rows_left){
        int pair = off + rbase + row_local;
        int token = tlist[pair];
        float p   = wlist[pair];
        int s     = slist[pair];
        float* srow = sel + ((size_t)s * TTOK + token) * ODIM + ct * 128 + wc * 64 + (lane & 15);
#pragma unroll
        for (int ni = 0; ni < 4; ni++)
          srow[ni * 16] = p * acc[mi][ni][r];
      }
    }
}

__global__ __launch_bounds__(256) void combine_kernel(
    const float4* __restrict__ s0, const float4* __restrict__ s1, float4* __restrict__ o)
{
  int i = blockIdx.x * 256 + threadIdx.x;
  float4 a = s0[i], b = s1[i];
  float4 r; r.x = a.x + b.x; r.y = a.y + b.y; r.z = a.z + b.z; r.w = a.w + b.w;
  o[i] = r;
}

extern "C" void kernel_launch(void* const* d_in, const int* in_sizes, int n_in,
                              void* d_out, int out_size, void* d_ws, size_t ws_size,
                              hipStream_t stream)
{
  const float* x  = (const float*)d_in[0];
  const float* rw = (const float*)d_in[1];
  const float* rb = (const float*)d_in[2];
  const float* W1 = (const float*)d_in[3];
  const float* W3 = (const float*)d_in[4];
  const float* W2 = (const float*)d_in[5];

  char* ws = (char*)d_ws;
  const size_t off_ctrl = 0;                                   // counts[8], cursor[8], offs[9]
  const size_t off_toke = 256;
  const size_t off_tokw = off_toke + (size_t)TTOK * 8;
  const size_t off_tl   = off_tokw + (size_t)TTOK * 8;
  const size_t off_wl   = off_tl   + (size_t)2 * TTOK * 4;
  const size_t off_sl   = off_wl   + (size_t)2 * TTOK * 4;
  const size_t off_xbf  = off_sl   + (size_t)2 * TTOK * 4;
  const size_t off_w1t  = off_xbf  + (size_t)TTOK * DIM * 2;
  const size_t off_w3t  = off_w1t  + (size_t)NE * HID * DIM * 2;
  const size_t off_w2t  = off_w3t  + (size_t)NE * HID * DIM * 2;
  const size_t off_ab   = off_w2t  + (size_t)NE * ODIM * HID * 2;
  const size_t off_sel  = off_ab   + (size_t)2 * TTOK * HID * 2;
  const size_t need     = off_sel  + (size_t)2 * TTOK * ODIM * 4;
  if (ws_size < need) return;  // workspace too small: leave output poisoned (visible failure)

  int* counts = (int*)(ws + off_ctrl);
  int* cursor = counts + 8;
  int* offs   = counts + 16;
  int2*   toke = (int2*)  (ws + off_toke);
  float2* tokw = (float2*)(ws + off_tokw);
  int*    tl   = (int*)   (ws + off_tl);
  float*  wl   = (float*) (ws + off_wl);
  int*    sl   = (int*)   (ws + off_sl);
  unsigned short* xbf = (unsigned short*)(ws + off_xbf);
  unsigned short* w1t = (unsigned short*)(ws + off_w1t);
  unsigned short* w3t = (unsigned short*)(ws + off_w3t);
  unsigned short* w2t = (unsigned short*)(ws + off_w2t);
  unsigned short* ab  = (unsigned short*)(ws + off_ab);
  float* sel = (float*)(ws + off_sel);

  hipMemsetAsync(ws + off_ctrl, 0, 64, stream);  // counts + cursor

  router_kernel<<<TTOK / 4, 256, 0, stream>>>(x, rw, rb, xbf, toke, tokw, counts);
  prefix_kernel<<<1, 64, 0, stream>>>(counts, offs);
  scatter_kernel<<<TTOK / 256, 256, 0, stream>>>(toke, tokw, offs, cursor, tl, wl, sl);

  transpose_cvt<<<dim3(HID / 64, DIM / 64, NE), 256, 0, stream>>>(W1, w1t, DIM, HID);
  transpose_cvt<<<dim3(HID / 64, DIM / 64, NE), 256, 0, stream>>>(W3, w3t, DIM, HID);
  transpose_cvt<<<dim3(ODIM / 64, HID / 64, NE), 256, 0, stream>>>(W2, w2t, HID, ODIM);

  ffn1_kernel<<<dim3(HID / 128, 32, NE), 256, 0, stream>>>(xbf, w1t, w3t, ab, counts, offs, tl);
  ffn2_kernel<<<dim3(ODIM / 128, 32, NE), 256, 0, stream>>>(ab, w2t, sel, counts, offs, tl, wl, sl);

  combine_kernel<<<(TTOK * ODIM / 4) / 256, 256, 0, stream>>>(
      (const float4*)sel, (const float4*)(sel + (size_t)TTOK * ODIM), (float4*)d_out);
}

// Round 2
// 390.743 us; speedup vs baseline: 1.0460x; 1.0460x over previous
//
#include <hip/hip_runtime.h>
#include <hip/hip_bf16.h>

#define TTOK 4096
#define DIM  1024
#define HID  2048
#define ODIM 1024
#define NE   8

typedef __attribute__((ext_vector_type(8))) short  short8;
typedef __attribute__((ext_vector_type(4))) float  f32x4;
typedef __attribute__((ext_vector_type(8))) unsigned short ushort8;

__device__ __forceinline__ unsigned short f2bf(float f){
  unsigned u = __float_as_uint(f);
  u += 0x7fffu + ((u >> 16) & 1u);
  return (unsigned short)(u >> 16);
}

__device__ __forceinline__ void gld16(const void* g, void* l){
  __builtin_amdgcn_global_load_lds(
      (const __attribute__((address_space(1))) unsigned int*)g,
      (__attribute__((address_space(3))) unsigned int*)l, 16, 0, 0);
}

// ---------------- router: logits(f32) -> top2 + weights, x -> bf16 ----------
__global__ __launch_bounds__(256) void router_kernel(
    const float* __restrict__ x, const float* __restrict__ rw,
    const float* __restrict__ rb, unsigned short* __restrict__ xbf,
    int2* __restrict__ toke, float2* __restrict__ tokw, int* __restrict__ counts)
{
  int tok  = (blockIdx.x * blockDim.x + threadIdx.x) >> 6;
  int lane = threadIdx.x & 63;
  const float4* xr = (const float4*)(x + (size_t)tok * DIM + lane * 16);
  float xv[16];
#pragma unroll
  for (int q = 0; q < 4; q++){
    float4 v = xr[q];
    xv[q*4+0]=v.x; xv[q*4+1]=v.y; xv[q*4+2]=v.z; xv[q*4+3]=v.w;
  }
  ushort8 u0, u1;
#pragma unroll
  for (int j = 0; j < 8; j++){ u0[j] = f2bf(xv[j]); u1[j] = f2bf(xv[8+j]); }
  ushort8* xo = (ushort8*)(xbf + (size_t)tok * DIM + lane * 16);
  xo[0] = u0; xo[1] = u1;

  float lg[NE];
#pragma unroll
  for (int e = 0; e < NE; e++){
    const float4* wr4 = (const float4*)(rw + (size_t)e * DIM + lane * 16);
    float s = 0.f;
#pragma unroll
    for (int q = 0; q < 4; q++){
      float4 wv = wr4[q];
      s += xv[q*4+0]*wv.x + xv[q*4+1]*wv.y + xv[q*4+2]*wv.z + xv[q*4+3]*wv.w;
    }
    lg[e] = s;
  }
#pragma unroll
  for (int e = 0; e < NE; e++)
    for (int s = 1; s < 64; s <<= 1) lg[e] += __shfl_xor(lg[e], s, 64);

  if (lane == 0){
#pragma unroll
    for (int e = 0; e < NE; e++) lg[e] += rb[e];
    int e0 = 0; float l0 = lg[0];
    for (int e = 1; e < NE; e++) if (lg[e] > l0){ l0 = lg[e]; e0 = e; }
    int e1 = -1; float l1 = -1e30f;
    for (int e = 0; e < NE; e++) if (e != e0 && lg[e] > l1){ l1 = lg[e]; e1 = e; }
    float w0 = 1.f / (1.f + __expf(l1 - l0));
    float w1 = 1.f / (1.f + __expf(l0 - l1));
    toke[tok] = make_int2(e0, e1);
    tokw[tok] = make_float2(w0, w1);
    atomicAdd(counts + e0, 1);
    atomicAdd(counts + e1, 1);
  }
}

__global__ void prefix_kernel(const int* __restrict__ counts, int* __restrict__ offs){
  if (threadIdx.x == 0){
    int a = 0;
    for (int e = 0; e < NE; e++){ offs[e] = a; a += counts[e]; }
    offs[NE] = a;
  }
}

__global__ __launch_bounds__(256) void scatter_kernel(
    const int2* __restrict__ toke, const float2* __restrict__ tokw,
    const int* __restrict__ offs, int* __restrict__ cursor,
    int* __restrict__ tlist, float* __restrict__ wlist, int* __restrict__ slist)
{
  int t = blockIdx.x * 256 + threadIdx.x;
  if (t >= TTOK) return;
  int2  e = toke[t];
  float2 w = tokw[t];
  int p0 = atomicAdd(cursor + e.x, 1);
  int i0 = offs[e.x] + p0;
  tlist[i0] = t; wlist[i0] = w.x; slist[i0] = 0;
  int p1 = atomicAdd(cursor + e.y, 1);
  int i1 = offs[e.y] + p1;
  tlist[i1] = t; wlist[i1] = w.y; slist[i1] = 1;
}

// ------- transpose+convert: in [E][R][C] f32 -> out [E][C][R] bf16 ----------
// tile 128 r x 64 c; LDS element (c,r) at byte c*256 + ((r>>3)^(c&15))*16 + (r&7)*2
__global__ __launch_bounds__(256) void transpose_cvt(
    const float* __restrict__ in, unsigned short* __restrict__ out, int R, int C)
{
  __shared__ __align__(16) unsigned short tl[64 * 128];
  int e = blockIdx.z;
  const float* src = in + (size_t)e * R * C + (size_t)(blockIdx.y * 128) * C + blockIdx.x * 64;
  unsigned short* dst = out + (size_t)e * C * R + (size_t)(blockIdx.x * 64) * R + blockIdx.y * 128;
  int t = threadIdx.x;
#pragma unroll
  for (int i = 0; i < 8; i++){
    int idx = i * 256 + t;
    int c = idx & 63, r0 = (idx >> 6) * 4;
    unsigned short v[4];
#pragma unroll
    for (int j = 0; j < 4; j++) v[j] = f2bf(src[(size_t)(r0 + j) * C + c]);
    unsigned long long pk = (unsigned long long)v[0] | ((unsigned long long)v[1] << 16)
      | ((unsigned long long)v[2] << 32) | ((unsigned long long)v[3] << 48);
    *(unsigned long long*)((char*)tl + c * 256 + (((r0 >> 3) ^ (c & 15)) * 16) + (r0 & 7) * 2) = pk;
  }
  __syncthreads();
#pragma unroll
  for (int i = 0; i < 4; i++){
    int idx = i * 256 + t;
    int c = idx >> 4, r0 = (idx & 15) * 8;
    ushort8 u = *(const ushort8*)((const char*)tl + c * 256 + (((r0 >> 3) ^ (c & 15)) * 16));
    *(ushort8*)(dst + (size_t)c * R + r0) = u;
  }
}

// ---------------- stage 1: h=X@W1, g=X@W3, a = silu(h)*g  (bf16) ------------
// LDS tile layout: row = 64B (32 bf16), 4 chunks of 16B; physical chunk =
// logical chunk ^ ((row>>1)&3).  Write side: pre-swizzled global source chunk
// (gld16 dest is linear).  Read side: swizzled fragment chunk.
__global__ __launch_bounds__(256,2) void ffn1_kernel(
    const unsigned short* __restrict__ xbf,
    const unsigned short* __restrict__ w1t,
    const unsigned short* __restrict__ w3t,
    unsigned short* __restrict__ abuf,
    const int* __restrict__ counts, const int* __restrict__ offs,
    const int* __restrict__ tlist)
{
  const int e = blockIdx.x, ct = blockIdx.y, rt = blockIdx.z;
  const int cnt = counts[e];
  const int rbase = rt * 128;
  if (rbase >= cnt) return;
  const int off = offs[e];
  const int rows_left = cnt - rbase;
  const int t = threadIdx.x;
  const int lane = t & 63, w = t >> 6;
  const int wr = w >> 1, wc = w & 1;

  __shared__ __align__(16) unsigned short As [128 * 32];
  __shared__ __align__(16) unsigned short B1s[128 * 32];
  __shared__ __align__(16) unsigned short B3s[128 * 32];

  int ar0 = t >> 2, ar1 = 64 + (t >> 2);
  int psw = (t & 3) ^ ((t >> 3) & 3);        // swizzled source chunk
  int ra0 = ar0 < rows_left ? ar0 : rows_left - 1;
  int ra1 = ar1 < rows_left ? ar1 : rows_left - 1;
  int tok0 = tlist[off + rbase + ra0];
  int tok1 = tlist[off + rbase + ra1];
  const char* sA0  = (const char*)xbf + ((size_t)tok0 * DIM) * 2 + psw * 16;
  const char* sA1  = (const char*)xbf + ((size_t)tok1 * DIM) * 2 + psw * 16;
  const char* sB10 = (const char*)w1t + (((size_t)e * HID + ct * 128 + ar0) * DIM) * 2 + psw * 16;
  const char* sB11 = (const char*)w1t + (((size_t)e * HID + ct * 128 + ar1) * DIM) * 2 + psw * 16;
  const char* sB30 = (const char*)w3t + (((size_t)e * HID + ct * 128 + ar0) * DIM) * 2 + psw * 16;
  const char* sB31 = (const char*)w3t + (((size_t)e * HID + ct * 128 + ar1) * DIM) * 2 + psw * 16;
  char* dA0  = (char*)As  + w * 1024;  char* dA1  = (char*)As  + 4096 + w * 1024;
  char* dB10 = (char*)B1s + w * 1024;  char* dB11 = (char*)B1s + 4096 + w * 1024;
  char* dB30 = (char*)B3s + w * 1024;  char* dB31 = (char*)B3s + 4096 + w * 1024;

  const int chsw = ((lane >> 4) ^ ((lane >> 1) & 3)) * 8;  // swizzled read chunk (elems)
  const unsigned short *ap[4], *b1p[4], *b3p[4];
#pragma unroll
  for (int i = 0; i < 4; i++){
    int am = wr * 64 + i * 16 + (lane & 15);
    int bn = wc * 64 + i * 16 + (lane & 15);
    ap[i]  = As  + am * 32 + chsw;
    b1p[i] = B1s + bn * 32 + chsw;
    b3p[i] = B3s + bn * 32 + chsw;
  }

  f32x4 acch[4][4], accg[4][4];
#pragma unroll
  for (int i = 0; i < 4; i++)
#pragma unroll
    for (int j = 0; j < 4; j++){
      acch[i][j] = (f32x4){0.f,0.f,0.f,0.f};
      accg[i][j] = (f32x4){0.f,0.f,0.f,0.f};
    }

  for (int kt = 0; kt < DIM / 32; ++kt){
    gld16(sA0,  dA0);  gld16(sA1,  dA1);
    gld16(sB10, dB10); gld16(sB11, dB11);
    gld16(sB30, dB30); gld16(sB31, dB31);
    sA0 += 64; sA1 += 64; sB10 += 64; sB11 += 64; sB30 += 64; sB31 += 64;
    __syncthreads();
    short8 a[4], b1[4], b3[4];
#pragma unroll
    for (int i = 0; i < 4; i++){
      a[i]  = *(const short8*)ap[i];
      b1[i] = *(const short8*)b1p[i];
      b3[i] = *(const short8*)b3p[i];
    }
#pragma unroll
    for (int mi = 0; mi < 4; mi++)
#pragma unroll
      for (int ni = 0; ni < 4; ni++){
        acch[mi][ni] = __builtin_amdgcn_mfma_f32_16x16x32_bf16(a[mi], b1[ni], acch[mi][ni], 0, 0, 0);
        accg[mi][ni] = __builtin_amdgcn_mfma_f32_16x16x32_bf16(a[mi], b3[ni], accg[mi][ni], 0, 0, 0);
      }
    __syncthreads();
  }

#pragma unroll
  for (int mi = 0; mi < 4; mi++)
#pragma unroll
    for (int r = 0; r < 4; r++){
      int row_local = wr * 64 + mi * 16 + ((lane >> 4) << 2) + r;
      if (row_local < rows_left){
        size_t pair = (size_t)(off + rbase + row_local);
        unsigned short* arow = abuf + pair * HID + ct * 128 + wc * 64 + (lane & 15);
#pragma unroll
        for (int ni = 0; ni < 4; ni++){
          float h = acch[mi][ni][r], g = accg[mi][ni][r];
          float sv = h / (1.f + __expf(-h));
          arow[ni * 16] = f2bf(sv * g);
        }
      }
    }
}

// ---------------- stage 2: eo = A @ W2, scaled atomic into d_out ------------
__global__ __launch_bounds__(256,2) void ffn2_kernel(
    const unsigned short* __restrict__ abuf,
    const unsigned short* __restrict__ w2t,
    float* __restrict__ dout,
    const int* __restrict__ counts, const int* __restrict__ offs,
    const int* __restrict__ tlist, const float* __restrict__ wlist)
{
  const int e = blockIdx.x, ct = blockIdx.y, rt = blockIdx.z;
  const int cnt = counts[e];
  const int rbase = rt * 128;
  if (rbase >= cnt) return;
  const int off = offs[e];
  const int rows_left = cnt - rbase;
  const int t = threadIdx.x;
  const int lane = t & 63, w = t >> 6;
  const int wr = w >> 1, wc = w & 1;

  __shared__ __align__(16) unsigned short As[128 * 32];
  __shared__ __align__(16) unsigned short Bs[128 * 32];

  int ar0 = t >> 2, ar1 = 64 + (t >> 2);
  int psw = (t & 3) ^ ((t >> 3) & 3);
  int ra0 = ar0 < rows_left ? ar0 : rows_left - 1;
  int ra1 = ar1 < rows_left ? ar1 : rows_left - 1;
  const char* sA0 = (const char*)abuf + ((size_t)(off + rbase + ra0) * HID) * 2 + psw * 16;
  const char* sA1 = (const char*)abuf + ((size_t)(off + rbase + ra1) * HID) * 2 + psw * 16;
  const char* sB0 = (const char*)w2t + (((size_t)e * ODIM + ct * 128 + ar0) * HID) * 2 + psw * 16;
  const char* sB1 = (const char*)w2t + (((size_t)e * ODIM + ct * 128 + ar1) * HID) * 2 + psw * 16;
  char* dA0 = (char*)As + w * 1024;  char* dA1 = (char*)As + 4096 + w * 1024;
  char* dB0 = (char*)Bs + w * 1024;  char* dB1 = (char*)Bs + 4096 + w * 1024;

  const int chsw = ((lane >> 4) ^ ((lane >> 1) & 3)) * 8;
  const unsigned short *ap[4], *bp[4];
#pragma unroll
  for (int i = 0; i < 4; i++){
    int am = wr * 64 + i * 16 + (lane & 15);
    int bn = wc * 64 + i * 16 + (lane & 15);
    ap[i] = As + am * 32 + chsw;
    bp[i] = Bs + bn * 32 + chsw;
  }

  f32x4 acc[4][4];
#pragma unroll
  for (int i = 0; i < 4; i++)
#pragma unroll
    for (int j = 0; j < 4; j++) acc[i][j] = (f32x4){0.f,0.f,0.f,0.f};

  for (int kt = 0; kt < HID / 32; ++kt){
    gld16(sA0, dA0); gld16(sA1, dA1);
    gld16(sB0, dB0); gld16(sB1, dB1);
    sA0 += 64; sA1 += 64; sB0 += 64; sB1 += 64;
    __syncthreads();
    short8 a[4], b[4];
#pragma unroll
    for (int i = 0; i < 4; i++){
      a[i] = *(const short8*)ap[i];
      b[i] = *(const short8*)bp[i];
    }
#pragma unroll
    for (int mi = 0; mi < 4; mi++)
#pragma unroll
      for (int ni = 0; ni < 4; ni++)
        acc[mi][ni] = __builtin_amdgcn_mfma_f32_16x16x32_bf16(a[mi], b[ni], acc[mi][ni], 0, 0, 0);
    __syncthreads();
  }

#pragma unroll
  for (int mi = 0; mi < 4; mi++)
#pragma unroll
    for (int r = 0; r < 4; r++){
      int row_local = wr * 64 + mi * 16 + ((lane >> 4) << 2) + r;
      if (row_local < rows_left){
        int pair = off + rbase + row_local;
        int token = tlist[pair];
        float p   = wlist[pair];
        float* orow = dout + (size_t)token * ODIM + ct * 128 + wc * 64 + (lane & 15);
#pragma unroll
        for (int ni = 0; ni < 4; ni++)
          atomicAdd(orow + ni * 16, p * acc[mi][ni][r]);
      }
    }
}

extern "C" void kernel_launch(void* const* d_in, const int* in_sizes, int n_in,
                              void* d_out, int out_size, void* d_ws, size_t ws_size,
                              hipStream_t stream)
{
  const float* x  = (const float*)d_in[0];
  const float* rw = (const float*)d_in[1];
  const float* rb = (const float*)d_in[2];
  const float* W1 = (const float*)d_in[3];
  const float* W3 = (const float*)d_in[4];
  const float* W2 = (const float*)d_in[5];

  char* ws = (char*)d_ws;
  const size_t off_ctrl = 0;                                   // counts[8], cursor[8], offs[9]
  const size_t off_toke = 256;
  const size_t off_tokw = off_toke + (size_t)TTOK * 8;
  const size_t off_tl   = off_tokw + (size_t)TTOK * 8;
  const size_t off_wl   = off_tl   + (size_t)2 * TTOK * 4;
  const size_t off_sl   = off_wl   + (size_t)2 * TTOK * 4;
  const size_t off_xbf  = off_sl   + (size_t)2 * TTOK * 4;
  const size_t off_w1t  = off_xbf  + (size_t)TTOK * DIM * 2;
  const size_t off_w3t  = off_w1t  + (size_t)NE * HID * DIM * 2;
  const size_t off_w2t  = off_w3t  + (size_t)NE * HID * DIM * 2;
  const size_t off_ab   = off_w2t  + (size_t)NE * ODIM * HID * 2;
  const size_t need     = off_ab   + (size_t)2 * TTOK * HID * 2;
  if (ws_size < need) return;  // workspace too small: leave output poisoned (visible failure)

  int* counts = (int*)(ws + off_ctrl);
  int* cursor = counts + 8;
  int* offs   = counts + 16;
  int2*   toke = (int2*)  (ws + off_toke);
  float2* tokw = (float2*)(ws + off_tokw);
  int*    tl   = (int*)   (ws + off_tl);
  float*  wl   = (float*) (ws + off_wl);
  int*    sl   = (int*)   (ws + off_sl);
  unsigned short* xbf = (unsigned short*)(ws + off_xbf);
  unsigned short* w1t = (unsigned short*)(ws + off_w1t);
  unsigned short* w3t = (unsigned short*)(ws + off_w3t);
  unsigned short* w2t = (unsigned short*)(ws + off_w2t);
  unsigned short* ab  = (unsigned short*)(ws + off_ab);

  hipMemsetAsync(ws + off_ctrl, 0, 64, stream);                  // counts + cursor
  hipMemsetAsync(d_out, 0, (size_t)out_size * sizeof(float), stream);

  router_kernel<<<TTOK / 4, 256, 0, stream>>>(x, rw, rb, xbf, toke, tokw, counts);
  prefix_kernel<<<1, 64, 0, stream>>>(counts, offs);
  scatter_kernel<<<TTOK / 256, 256, 0, stream>>>(toke, tokw, offs, cursor, tl, wl, sl);

  transpose_cvt<<<dim3(HID / 64, DIM / 128, NE), 256, 0, stream>>>(W1, w1t, DIM, HID);
  transpose_cvt<<<dim3(HID / 64, DIM / 128, NE), 256, 0, stream>>>(W3, w3t, DIM, HID);
  transpose_cvt<<<dim3(ODIM / 64, HID / 128, NE), 256, 0, stream>>>(W2, w2t, HID, ODIM);

  ffn1_kernel<<<dim3(NE, HID / 128, 64), 256, 0, stream>>>(xbf, w1t, w3t, ab, counts, offs, tl);
  ffn2_kernel<<<dim3(NE, ODIM / 128, 64), 256, 0, stream>>>(ab, w2t, (float*)d_out, counts, offs, tl, wl);
}

// Round 3
// 376.558 us; speedup vs baseline: 1.0854x; 1.0377x over previous
//
#include <hip/hip_runtime.h>
#include <hip/hip_bf16.h>

#define TTOK 4096
#define DIM  1024
#define HID  2048
#define ODIM 1024
#define NE   8

typedef __attribute__((ext_vector_type(8))) short  short8;
typedef __attribute__((ext_vector_type(4))) float  f32x4;
typedef __attribute__((ext_vector_type(8))) unsigned short ushort8;

__device__ __forceinline__ unsigned short f2bf(float f){
  unsigned u = __float_as_uint(f);
  u += 0x7fffu + ((u >> 16) & 1u);
  return (unsigned short)(u >> 16);
}

__device__ __forceinline__ void gld16(const void* g, void* l){
  __builtin_amdgcn_global_load_lds(
      (const __attribute__((address_space(1))) unsigned int*)g,
      (__attribute__((address_space(3))) unsigned int*)l, 16, 0, 0);
}

// ---------------- router: logits(f32) -> top2 + weights, x -> bf16 ----------
__global__ __launch_bounds__(256) void router_kernel(
    const float* __restrict__ x, const float* __restrict__ rw,
    const float* __restrict__ rb, unsigned short* __restrict__ xbf,
    int2* __restrict__ toke, float2* __restrict__ tokw, int* __restrict__ counts)
{
  int tok  = (blockIdx.x * blockDim.x + threadIdx.x) >> 6;
  int lane = threadIdx.x & 63;
  const float4* xr = (const float4*)(x + (size_t)tok * DIM + lane * 16);
  float xv[16];
#pragma unroll
  for (int q = 0; q < 4; q++){
    float4 v = xr[q];
    xv[q*4+0]=v.x; xv[q*4+1]=v.y; xv[q*4+2]=v.z; xv[q*4+3]=v.w;
  }
  ushort8 u0, u1;
#pragma unroll
  for (int j = 0; j < 8; j++){ u0[j] = f2bf(xv[j]); u1[j] = f2bf(xv[8+j]); }
  ushort8* xo = (ushort8*)(xbf + (size_t)tok * DIM + lane * 16);
  xo[0] = u0; xo[1] = u1;

  float lg[NE];
#pragma unroll
  for (int e = 0; e < NE; e++){
    const float4* wr4 = (const float4*)(rw + (size_t)e * DIM + lane * 16);
    float s = 0.f;
#pragma unroll
    for (int q = 0; q < 4; q++){
      float4 wv = wr4[q];
      s += xv[q*4+0]*wv.x + xv[q*4+1]*wv.y + xv[q*4+2]*wv.z + xv[q*4+3]*wv.w;
    }
    lg[e] = s;
  }
#pragma unroll
  for (int e = 0; e < NE; e++)
    for (int s = 1; s < 64; s <<= 1) lg[e] += __shfl_xor(lg[e], s, 64);

  if (lane == 0){
#pragma unroll
    for (int e = 0; e < NE; e++) lg[e] += rb[e];
    int e0 = 0; float l0 = lg[0];
    for (int e = 1; e < NE; e++) if (lg[e] > l0){ l0 = lg[e]; e0 = e; }
    int e1 = -1; float l1 = -1e30f;
    for (int e = 0; e < NE; e++) if (e != e0 && lg[e] > l1){ l1 = lg[e]; e1 = e; }
    float w0 = 1.f / (1.f + __expf(l1 - l0));
    float w1 = 1.f / (1.f + __expf(l0 - l1));
    toke[tok] = make_int2(e0, e1);
    tokw[tok] = make_float2(w0, w1);
    atomicAdd(counts + e0, 1);
    atomicAdd(counts + e1, 1);
  }
}

__global__ void prefix_kernel(const int* __restrict__ counts, int* __restrict__ offs){
  if (threadIdx.x == 0){
    int a = 0;
    for (int e = 0; e < NE; e++){ offs[e] = a; a += counts[e]; }
    offs[NE] = a;
  }
}

__global__ __launch_bounds__(256) void scatter_kernel(
    const int2* __restrict__ toke, const float2* __restrict__ tokw,
    const int* __restrict__ offs, int* __restrict__ cursor,
    int* __restrict__ tlist, float* __restrict__ wlist, int* __restrict__ slist)
{
  int t = blockIdx.x * 256 + threadIdx.x;
  if (t >= TTOK) return;
  int2  e = toke[t];
  float2 w = tokw[t];
  int p0 = atomicAdd(cursor + e.x, 1);
  int i0 = offs[e.x] + p0;
  tlist[i0] = t; wlist[i0] = w.x; slist[i0] = 0;
  int p1 = atomicAdd(cursor + e.y, 1);
  int i1 = offs[e.y] + p1;
  tlist[i1] = t; wlist[i1] = w.y; slist[i1] = 1;
}

// ------- transpose+convert: in [E][R][C] f32 -> out [E][C][R] bf16 ----------
// tile 128 r x 64 c; LDS element (c,r) at byte c*256 + ((r>>3)^(c&15))*16 + (r&7)*2
__global__ __launch_bounds__(256) void transpose_cvt(
    const float* __restrict__ in, unsigned short* __restrict__ out, int R, int C)
{
  __shared__ __align__(16) unsigned short tl[64 * 128];
  int e = blockIdx.z;
  const float* src = in + (size_t)e * R * C + (size_t)(blockIdx.y * 128) * C + blockIdx.x * 64;
  unsigned short* dst = out + (size_t)e * C * R + (size_t)(blockIdx.x * 64) * R + blockIdx.y * 128;
  int t = threadIdx.x;
#pragma unroll
  for (int i = 0; i < 8; i++){
    int idx = i * 256 + t;
    int c = idx & 63, r0 = (idx >> 6) * 4;
    unsigned short v[4];
#pragma unroll
    for (int j = 0; j < 4; j++) v[j] = f2bf(src[(size_t)(r0 + j) * C + c]);
    unsigned long long pk = (unsigned long long)v[0] | ((unsigned long long)v[1] << 16)
      | ((unsigned long long)v[2] << 32) | ((unsigned long long)v[3] << 48);
    *(unsigned long long*)((char*)tl + c * 256 + (((r0 >> 3) ^ (c & 15)) * 16) + (r0 & 7) * 2) = pk;
  }
  __syncthreads();
#pragma unroll
  for (int i = 0; i < 4; i++){
    int idx = i * 256 + t;
    int c = idx >> 4, r0 = (idx & 15) * 8;
    ushort8 u = *(const ushort8*)((const char*)tl + c * 256 + (((r0 >> 3) ^ (c & 15)) * 16));
    *(ushort8*)(dst + (size_t)c * R + r0) = u;
  }
}

// ---------------- stage 1: h=X@W1, g=X@W3, a = silu(h)*g  (bf16) ------------
// Double-buffered LDS, ONE barrier per K-step, STAGE issued before compute so
// the __syncthreads vmcnt(0) drain lands after the MFMA cluster (T3-minimum).
// LDS chunk swizzle: physical 16B chunk = logical ^ ((row>>1)&3), both sides.
__global__ __launch_bounds__(256,2) void ffn1_kernel(
    const unsigned short* __restrict__ xbf,
    const unsigned short* __restrict__ w1t,
    const unsigned short* __restrict__ w3t,
    unsigned short* __restrict__ abuf,
    const int* __restrict__ counts, const int* __restrict__ offs,
    const int* __restrict__ tlist)
{
  const int e = blockIdx.x, ct = blockIdx.y, rt = blockIdx.z;
  const int cnt = counts[e];
  const int rbase = rt * 128;
  if (rbase >= cnt) return;
  const int off = offs[e];
  const int rows_left = cnt - rbase;
  const int t = threadIdx.x;
  const int lane = t & 63, w = t >> 6;
  const int wr = w >> 1, wc = w & 1;

  // [2 buffers][A:4096 | B1:4096 | B3:4096 elems] = 48 KB total
  __shared__ __align__(16) unsigned short lds[2 * 12288];

  int ar0 = t >> 2, ar1 = 64 + (t >> 2);
  int psw = (t & 3) ^ ((t >> 3) & 3);        // pre-swizzled source chunk
  int ra0 = ar0 < rows_left ? ar0 : rows_left - 1;
  int ra1 = ar1 < rows_left ? ar1 : rows_left - 1;
  int tok0 = tlist[off + rbase + ra0];
  int tok1 = tlist[off + rbase + ra1];
  const char* sA0  = (const char*)xbf + ((size_t)tok0 * DIM) * 2 + psw * 16;
  const char* sA1  = (const char*)xbf + ((size_t)tok1 * DIM) * 2 + psw * 16;
  const char* sB10 = (const char*)w1t + (((size_t)e * HID + ct * 128 + ar0) * DIM) * 2 + psw * 16;
  const char* sB11 = (const char*)w1t + (((size_t)e * HID + ct * 128 + ar1) * DIM) * 2 + psw * 16;
  const char* sB30 = (const char*)w3t + (((size_t)e * HID + ct * 128 + ar0) * DIM) * 2 + psw * 16;
  const char* sB31 = (const char*)w3t + (((size_t)e * HID + ct * 128 + ar1) * DIM) * 2 + psw * 16;
  const int dofs = w * 1024;                  // byte offset within region

  auto STAGE = [&](int bs, int kt){
    int kb = kt << 6;                         // 64 B per K-step of 32 bf16
    char* base = (char*)lds + bs * 24576;
    gld16(sA0  + kb, base +            dofs);
    gld16(sA1  + kb, base +  4096 +    dofs);
    gld16(sB10 + kb, base +  8192 +    dofs);
    gld16(sB11 + kb, base + 12288 +    dofs);
    gld16(sB30 + kb, base + 16384 +    dofs);
    gld16(sB31 + kb, base + 20480 +    dofs);
  };

  const int chsw = ((lane >> 4) ^ ((lane >> 1) & 3)) * 8;  // swizzled read chunk
  int aofs[4], b1ofs[4], b3ofs[4];
#pragma unroll
  for (int i = 0; i < 4; i++){
    int am = wr * 64 + i * 16 + (lane & 15);
    int bn = wc * 64 + i * 16 + (lane & 15);
    aofs[i]  = am * 32 + chsw;
    b1ofs[i] = 4096 + bn * 32 + chsw;
    b3ofs[i] = 8192 + bn * 32 + chsw;
  }

  f32x4 acch[4][4], accg[4][4];
#pragma unroll
  for (int i = 0; i < 4; i++)
#pragma unroll
    for (int j = 0; j < 4; j++){
      acch[i][j] = (f32x4){0.f,0.f,0.f,0.f};
      accg[i][j] = (f32x4){0.f,0.f,0.f,0.f};
    }

  STAGE(0, 0);
  __syncthreads();
#pragma unroll 2
  for (int kt = 0; kt + 1 < DIM / 32; ++kt){
    const int bs = kt & 1;
    STAGE(bs ^ 1, kt + 1);
    const unsigned short* L = lds + bs * 12288;
    short8 a[4], b1[4], b3[4];
#pragma unroll
    for (int i = 0; i < 4; i++){
      a[i]  = *(const short8*)(L + aofs[i]);
      b1[i] = *(const short8*)(L + b1ofs[i]);
      b3[i] = *(const short8*)(L + b3ofs[i]);
    }
#pragma unroll
    for (int mi = 0; mi < 4; mi++)
#pragma unroll
      for (int ni = 0; ni < 4; ni++){
        acch[mi][ni] = __builtin_amdgcn_mfma_f32_16x16x32_bf16(a[mi], b1[ni], acch[mi][ni], 0, 0, 0);
        accg[mi][ni] = __builtin_amdgcn_mfma_f32_16x16x32_bf16(a[mi], b3[ni], accg[mi][ni], 0, 0, 0);
      }
    __syncthreads();          // drains vmcnt(0) AFTER the MFMA cluster
  }
  {
    const int bs = (DIM / 32 - 1) & 1;
    const unsigned short* L = lds + bs * 12288;
    short8 a[4], b1[4], b3[4];
#pragma unroll
    for (int i = 0; i < 4; i++){
      a[i]  = *(const short8*)(L + aofs[i]);
      b1[i] = *(const short8*)(L + b1ofs[i]);
      b3[i] = *(const short8*)(L + b3ofs[i]);
    }
#pragma unroll
    for (int mi = 0; mi < 4; mi++)
#pragma unroll
      for (int ni = 0; ni < 4; ni++){
        acch[mi][ni] = __builtin_amdgcn_mfma_f32_16x16x32_bf16(a[mi], b1[ni], acch[mi][ni], 0, 0, 0);
        accg[mi][ni] = __builtin_amdgcn_mfma_f32_16x16x32_bf16(a[mi], b3[ni], accg[mi][ni], 0, 0, 0);
      }
  }

#pragma unroll
  for (int mi = 0; mi < 4; mi++)
#pragma unroll
    for (int r = 0; r < 4; r++){
      int row_local = wr * 64 + mi * 16 + ((lane >> 4) << 2) + r;
      if (row_local < rows_left){
        size_t pair = (size_t)(off + rbase + row_local);
        unsigned short* arow = abuf + pair * HID + ct * 128 + wc * 64 + (lane & 15);
#pragma unroll
        for (int ni = 0; ni < 4; ni++){
          float h = acch[mi][ni][r], g = accg[mi][ni][r];
          float sv = h / (1.f + __expf(-h));
          arow[ni * 16] = f2bf(sv * g);
        }
      }
    }
}

// ---------------- stage 2: eo = A @ W2, scaled atomic into d_out ------------
__global__ __launch_bounds__(256,2) void ffn2_kernel(
    const unsigned short* __restrict__ abuf,
    const unsigned short* __restrict__ w2t,
    float* __restrict__ dout,
    const int* __restrict__ counts, const int* __restrict__ offs,
    const int* __restrict__ tlist, const float* __restrict__ wlist)
{
  const int e = blockIdx.x, ct = blockIdx.y, rt = blockIdx.z;
  const int cnt = counts[e];
  const int rbase = rt * 128;
  if (rbase >= cnt) return;
  const int off = offs[e];
  const int rows_left = cnt - rbase;
  const int t = threadIdx.x;
  const int lane = t & 63, w = t >> 6;
  const int wr = w >> 1, wc = w & 1;

  // [2 buffers][A:4096 | B:4096 elems] = 32 KB total
  __shared__ __align__(16) unsigned short lds[2 * 8192];

  int ar0 = t >> 2, ar1 = 64 + (t >> 2);
  int psw = (t & 3) ^ ((t >> 3) & 3);
  int ra0 = ar0 < rows_left ? ar0 : rows_left - 1;
  int ra1 = ar1 < rows_left ? ar1 : rows_left - 1;
  const char* sA0 = (const char*)abuf + ((size_t)(off + rbase + ra0) * HID) * 2 + psw * 16;
  const char* sA1 = (const char*)abuf + ((size_t)(off + rbase + ra1) * HID) * 2 + psw * 16;
  const char* sB0 = (const char*)w2t + (((size_t)e * ODIM + ct * 128 + ar0) * HID) * 2 + psw * 16;
  const char* sB1 = (const char*)w2t + (((size_t)e * ODIM + ct * 128 + ar1) * HID) * 2 + psw * 16;
  const int dofs = w * 1024;

  auto STAGE = [&](int bs, int kt){
    int kb = kt << 6;
    char* base = (char*)lds + bs * 16384;
    gld16(sA0 + kb, base +           dofs);
    gld16(sA1 + kb, base +  4096 +   dofs);
    gld16(sB0 + kb, base +  8192 +   dofs);
    gld16(sB1 + kb, base + 12288 +   dofs);
  };

  const int chsw = ((lane >> 4) ^ ((lane >> 1) & 3)) * 8;
  int aofs[4], bofs[4];
#pragma unroll
  for (int i = 0; i < 4; i++){
    int am = wr * 64 + i * 16 + (lane & 15);
    int bn = wc * 64 + i * 16 + (lane & 15);
    aofs[i] = am * 32 + chsw;
    bofs[i] = 4096 + bn * 32 + chsw;
  }

  f32x4 acc[4][4];
#pragma unroll
  for (int i = 0; i < 4; i++)
#pragma unroll
    for (int j = 0; j < 4; j++) acc[i][j] = (f32x4){0.f,0.f,0.f,0.f};

  STAGE(0, 0);
  __syncthreads();
#pragma unroll 2
  for (int kt = 0; kt + 1 < HID / 32; ++kt){
    const int bs = kt & 1;
    STAGE(bs ^ 1, kt + 1);
    const unsigned short* L = lds + bs * 8192;
    short8 a[4], b[4];
#pragma unroll
    for (int i = 0; i < 4; i++){
      a[i] = *(const short8*)(L + aofs[i]);
      b[i] = *(const short8*)(L + bofs[i]);
    }
#pragma unroll
    for (int mi = 0; mi < 4; mi++)
#pragma unroll
      for (int ni = 0; ni < 4; ni++)
        acc[mi][ni] = __builtin_amdgcn_mfma_f32_16x16x32_bf16(a[mi], b[ni], acc[mi][ni], 0, 0, 0);
    __syncthreads();
  }
  {
    const int bs = (HID / 32 - 1) & 1;
    const unsigned short* L = lds + bs * 8192;
    short8 a[4], b[4];
#pragma unroll
    for (int i = 0; i < 4; i++){
      a[i] = *(const short8*)(L + aofs[i]);
      b[i] = *(const short8*)(L + bofs[i]);
    }
#pragma unroll
    for (int mi = 0; mi < 4; mi++)
#pragma unroll
      for (int ni = 0; ni < 4; ni++)
        acc[mi][ni] = __builtin_amdgcn_mfma_f32_16x16x32_bf16(a[mi], b[ni], acc[mi][ni], 0, 0, 0);
  }

#pragma unroll
  for (int mi = 0; mi < 4; mi++)
#pragma unroll
    for (int r = 0; r < 4; r++){
      int row_local = wr * 64 + mi * 16 + ((lane >> 4) << 2) + r;
      if (row_local < rows_left){
        int pair = off + rbase + row_local;
        int token = tlist[pair];
        float p   = wlist[pair];
        float* orow = dout + (size_t)token * ODIM + ct * 128 + wc * 64 + (lane & 15);
#pragma unroll
        for (int ni = 0; ni < 4; ni++)
          atomicAdd(orow + ni * 16, p * acc[mi][ni][r]);
      }
    }
}

extern "C" void kernel_launch(void* const* d_in, const int* in_sizes, int n_in,
                              void* d_out, int out_size, void* d_ws, size_t ws_size,
                              hipStream_t stream)
{
  const float* x  = (const float*)d_in[0];
  const float* rw = (const float*)d_in[1];
  const float* rb = (const float*)d_in[2];
  const float* W1 = (const float*)d_in[3];
  const float* W3 = (const float*)d_in[4];
  const float* W2 = (const float*)d_in[5];

  char* ws = (char*)d_ws;
  const size_t off_ctrl = 0;                                   // counts[8], cursor[8], offs[9]
  const size_t off_toke = 256;
  const size_t off_tokw = off_toke + (size_t)TTOK * 8;
  const size_t off_tl   = off_tokw + (size_t)TTOK * 8;
  const size_t off_wl   = off_tl   + (size_t)2 * TTOK * 4;
  const size_t off_sl   = off_wl   + (size_t)2 * TTOK * 4;
  const size_t off_xbf  = off_sl   + (size_t)2 * TTOK * 4;
  const size_t off_w1t  = off_xbf  + (size_t)TTOK * DIM * 2;
  const size_t off_w3t  = off_w1t  + (size_t)NE * HID * DIM * 2;
  const size_t off_w2t  = off_w3t  + (size_t)NE * HID * DIM * 2;
  const size_t off_ab   = off_w2t  + (size_t)NE * ODIM * HID * 2;
  const size_t need     = off_ab   + (size_t)2 * TTOK * HID * 2;
  if (ws_size < need) return;  // workspace too small: leave output poisoned (visible failure)

  int* counts = (int*)(ws + off_ctrl);
  int* cursor = counts + 8;
  int* offs   = counts + 16;
  int2*   toke = (int2*)  (ws + off_toke);
  float2* tokw = (float2*)(ws + off_tokw);
  int*    tl   = (int*)   (ws + off_tl);
  float*  wl   = (float*) (ws + off_wl);
  int*    sl   = (int*)   (ws + off_sl);
  unsigned short* xbf = (unsigned short*)(ws + off_xbf);
  unsigned short* w1t = (unsigned short*)(ws + off_w1t);
  unsigned short* w3t = (unsigned short*)(ws + off_w3t);
  unsigned short* w2t = (unsigned short*)(ws + off_w2t);
  unsigned short* ab  = (unsigned short*)(ws + off_ab);

  hipMemsetAsync(ws + off_ctrl, 0, 64, stream);                  // counts + cursor
  hipMemsetAsync(d_out, 0, (size_t)out_size * sizeof(float), stream);

  router_kernel<<<TTOK / 4, 256, 0, stream>>>(x, rw, rb, xbf, toke, tokw, counts);
  prefix_kernel<<<1, 64, 0, stream>>>(counts, offs);
  scatter_kernel<<<TTOK / 256, 256, 0, stream>>>(toke, tokw, offs, cursor, tl, wl, sl);

  transpose_cvt<<<dim3(HID / 64, DIM / 128, NE), 256, 0, stream>>>(W1, w1t, DIM, HID);
  transpose_cvt<<<dim3(HID / 64, DIM / 128, NE), 256, 0, stream>>>(W3, w3t, DIM, HID);
  transpose_cvt<<<dim3(ODIM / 64, HID / 128, NE), 256, 0, stream>>>(W2, w2t, HID, ODIM);

  ffn1_kernel<<<dim3(NE, HID / 128, 32), 256, 0, stream>>>(xbf, w1t, w3t, ab, counts, offs, tl);
  ffn2_kernel<<<dim3(NE, ODIM / 128, 32), 256, 0, stream>>>(ab, w2t, (float*)d_out, counts, offs, tl, wl);
}

// Round 4
// 251.987 us; speedup vs baseline: 1.6220x; 1.4944x over previous
//
#include <hip/hip_runtime.h>
#include <hip/hip_bf16.h>

#define TTOK 4096
#define DIM  1024
#define HID  2048
#define ODIM 1024
#define NE   8

typedef __attribute__((ext_vector_type(8))) short  short8;
typedef __attribute__((ext_vector_type(4))) float  f32x4;
typedef __attribute__((ext_vector_type(8))) unsigned short ushort8;

__device__ __forceinline__ unsigned short f2bf(float f){
  unsigned u = __float_as_uint(f);
  u += 0x7fffu + ((u >> 16) & 1u);
  return (unsigned short)(u >> 16);
}

__device__ __forceinline__ void gld16(const void* g, void* l){
  __builtin_amdgcn_global_load_lds(
      (const __attribute__((address_space(1))) unsigned int*)g,
      (__attribute__((address_space(3))) unsigned int*)l, 16, 0, 0);
}

// ---------------- router: logits(f32) -> top2 + weights, x -> bf16 ----------
// NO atomics: counts/offsets/scatter are derived later by plan_kernel.
__global__ __launch_bounds__(256) void router_kernel(
    const float* __restrict__ x, const float* __restrict__ rw,
    const float* __restrict__ rb, unsigned short* __restrict__ xbf,
    int2* __restrict__ toke, float2* __restrict__ tokw)
{
  int tok  = (blockIdx.x * blockDim.x + threadIdx.x) >> 6;
  int lane = threadIdx.x & 63;
  const float4* xr = (const float4*)(x + (size_t)tok * DIM + lane * 16);
  float xv[16];
#pragma unroll
  for (int q = 0; q < 4; q++){
    float4 v = xr[q];
    xv[q*4+0]=v.x; xv[q*4+1]=v.y; xv[q*4+2]=v.z; xv[q*4+3]=v.w;
  }
  ushort8 u0, u1;
#pragma unroll
  for (int j = 0; j < 8; j++){ u0[j] = f2bf(xv[j]); u1[j] = f2bf(xv[8+j]); }
  ushort8* xo = (ushort8*)(xbf + (size_t)tok * DIM + lane * 16);
  xo[0] = u0; xo[1] = u1;

  float lg[NE];
#pragma unroll
  for (int e = 0; e < NE; e++){
    const float4* wr4 = (const float4*)(rw + (size_t)e * DIM + lane * 16);
    float s = 0.f;
#pragma unroll
    for (int q = 0; q < 4; q++){
      float4 wv = wr4[q];
      s += xv[q*4+0]*wv.x + xv[q*4+1]*wv.y + xv[q*4+2]*wv.z + xv[q*4+3]*wv.w;
    }
    lg[e] = s;
  }
#pragma unroll
  for (int e = 0; e < NE; e++)
    for (int s = 1; s < 64; s <<= 1) lg[e] += __shfl_xor(lg[e], s, 64);

  if (lane == 0){
#pragma unroll
    for (int e = 0; e < NE; e++) lg[e] += rb[e];
    int e0 = 0; float l0 = lg[0];
    for (int e = 1; e < NE; e++) if (lg[e] > l0){ l0 = lg[e]; e0 = e; }
    int e1 = -1; float l1 = -1e30f;
    for (int e = 0; e < NE; e++) if (e != e0 && lg[e] > l1){ l1 = lg[e]; e1 = e; }
    float w0 = 1.f / (1.f + __expf(l1 - l0));
    float w1 = 1.f / (1.f + __expf(l0 - l1));
    toke[tok] = make_int2(e0, e1);
    tokw[tok] = make_float2(w0, w1);
  }
}

// ---- plan: per-expert compact lists, counts, offsets. Atomic-free. ---------
// 8 blocks; block e reads all toke pairs, histograms all experts via ballot,
// derives its own offset, then scatters expert e's (token,weight) list in
// token order via ballot-rank + cross-wave LDS scan. Deterministic.
__global__ __launch_bounds__(256) void plan_kernel(
    const int2* __restrict__ toke, const float2* __restrict__ tokw,
    int* __restrict__ counts, int* __restrict__ offs,
    int* __restrict__ tlist, float* __restrict__ wlist)
{
  const int e  = blockIdx.x;
  const int t  = threadIdx.x;
  const int lane = t & 63, wv = t >> 6;
  __shared__ int sh[4 * 8];
  __shared__ int tot[8];
  __shared__ int sw[4];

  // pass 1: full histogram (every block computes all 8 counts)
  int wcnt[NE];
#pragma unroll
  for (int ee = 0; ee < NE; ee++) wcnt[ee] = 0;
  for (int base = 0; base < TTOK; base += 256){
    int2 p = toke[base + t];
#pragma unroll
    for (int ee = 0; ee < NE; ee++){
      unsigned long long m = __ballot(p.x == ee || p.y == ee);
      if (lane == 0) wcnt[ee] += __popcll(m);
    }
  }
  if (lane == 0){
#pragma unroll
    for (int ee = 0; ee < NE; ee++) sh[wv * 8 + ee] = wcnt[ee];
  }
  __syncthreads();
  if (t < NE) tot[t] = sh[t] + sh[8 + t] + sh[16 + t] + sh[24 + t];
  __syncthreads();

  int my_off = 0;
#pragma unroll
  for (int ee = 0; ee < NE; ee++) if (ee < e) my_off += tot[ee];

  if (e == 0 && t < NE){
    counts[t] = tot[t];
    int o = 0;
    for (int ee = 0; ee < NE; ee++){ if (ee < t) o += tot[ee]; }
    offs[t] = o;
    if (t == 0){
      int s = 0;
      for (int ee = 0; ee < NE; ee++) s += tot[ee];
      offs[NE] = s;
    }
  }

  // pass 2: scatter expert e's tokens in ascending token order
  int running = my_off;
  for (int base = 0; base < TTOK; base += 256){
    int tokid = base + t;
    int2  p = toke[tokid];
    float2 wgt = tokw[tokid];
    bool s0 = (p.x == e), s1 = (p.y == e);
    bool flag = s0 || s1;
    unsigned long long m = __ballot(flag);
    int rank_in_wave = __popcll(m & ((lane == 0) ? 0ull : ((~0ull) >> (64 - lane))));
    if (lane == 0) sw[wv] = __popcll(m);
    __syncthreads();
    int wave_base = 0, tot4 = 0;
#pragma unroll
    for (int w2 = 0; w2 < 4; w2++){ int v = sw[w2]; tot4 += v; if (w2 < wv) wave_base += v; }
    if (flag){
      int pos = running + wave_base + rank_in_wave;
      tlist[pos] = tokid;
      wlist[pos] = s0 ? wgt.x : wgt.y;
    }
    running += tot4;
    __syncthreads();
  }
}

// ------- transpose+convert: in [E][R][C] f32 -> out [E][C][R] bf16 ----------
// tile 128 r x 64 c; LDS element (c,r) at byte c*256 + ((r>>3)^(c&15))*16 + (r&7)*2
__global__ __launch_bounds__(256) void transpose_cvt(
    const float* __restrict__ in, unsigned short* __restrict__ out, int R, int C)
{
  __shared__ __align__(16) unsigned short tl[64 * 128];
  int e = blockIdx.z;
  const float* src = in + (size_t)e * R * C + (size_t)(blockIdx.y * 128) * C + blockIdx.x * 64;
  unsigned short* dst = out + (size_t)e * C * R + (size_t)(blockIdx.x * 64) * R + blockIdx.y * 128;
  int t = threadIdx.x;
#pragma unroll
  for (int i = 0; i < 8; i++){
    int idx = i * 256 + t;
    int c = idx & 63, r0 = (idx >> 6) * 4;
    unsigned short v[4];
#pragma unroll
    for (int j = 0; j < 4; j++) v[j] = f2bf(src[(size_t)(r0 + j) * C + c]);
    unsigned long long pk = (unsigned long long)v[0] | ((unsigned long long)v[1] << 16)
      | ((unsigned long long)v[2] << 32) | ((unsigned long long)v[3] << 48);
    *(unsigned long long*)((char*)tl + c * 256 + (((r0 >> 3) ^ (c & 15)) * 16) + (r0 & 7) * 2) = pk;
  }
  __syncthreads();
#pragma unroll
  for (int i = 0; i < 4; i++){
    int idx = i * 256 + t;
    int c = idx >> 4, r0 = (idx & 15) * 8;
    ushort8 u = *(const ushort8*)((const char*)tl + c * 256 + (((r0 >> 3) ^ (c & 15)) * 16));
    *(ushort8*)(dst + (size_t)c * R + r0) = u;
  }
}

// ---------------- stage 1: h=X@W1, g=X@W3, a = silu(h)*g  (bf16) ------------
// Double-buffered LDS, ONE barrier per K-step, STAGE issued before compute so
// the __syncthreads vmcnt(0) drain lands after the MFMA cluster (T3-minimum).
// LDS chunk swizzle: physical 16B chunk = logical ^ ((row>>1)&3), both sides.
__global__ __launch_bounds__(256,2) void ffn1_kernel(
    const unsigned short* __restrict__ xbf,
    const unsigned short* __restrict__ w1t,
    const unsigned short* __restrict__ w3t,
    unsigned short* __restrict__ abuf,
    const int* __restrict__ counts, const int* __restrict__ offs,
    const int* __restrict__ tlist)
{
  const int e = blockIdx.x, ct = blockIdx.y, rt = blockIdx.z;
  const int cnt = counts[e];
  const int rbase = rt * 128;
  if (rbase >= cnt) return;
  const int off = offs[e];
  const int rows_left = cnt - rbase;
  const int t = threadIdx.x;
  const int lane = t & 63, w = t >> 6;
  const int wr = w >> 1, wc = w & 1;

  // [2 buffers][A:4096 | B1:4096 | B3:4096 elems] = 48 KB total
  __shared__ __align__(16) unsigned short lds[2 * 12288];

  int ar0 = t >> 2, ar1 = 64 + (t >> 2);
  int psw = (t & 3) ^ ((t >> 3) & 3);        // pre-swizzled source chunk
  int ra0 = ar0 < rows_left ? ar0 : rows_left - 1;
  int ra1 = ar1 < rows_left ? ar1 : rows_left - 1;
  int tok0 = tlist[off + rbase + ra0];
  int tok1 = tlist[off + rbase + ra1];
  const char* sA0  = (const char*)xbf + ((size_t)tok0 * DIM) * 2 + psw * 16;
  const char* sA1  = (const char*)xbf + ((size_t)tok1 * DIM) * 2 + psw * 16;
  const char* sB10 = (const char*)w1t + (((size_t)e * HID + ct * 128 + ar0) * DIM) * 2 + psw * 16;
  const char* sB11 = (const char*)w1t + (((size_t)e * HID + ct * 128 + ar1) * DIM) * 2 + psw * 16;
  const char* sB30 = (const char*)w3t + (((size_t)e * HID + ct * 128 + ar0) * DIM) * 2 + psw * 16;
  const char* sB31 = (const char*)w3t + (((size_t)e * HID + ct * 128 + ar1) * DIM) * 2 + psw * 16;
  const int dofs = w * 1024;                  // byte offset within region

  auto STAGE = [&](int bs, int kt){
    int kb = kt << 6;                         // 64 B per K-step of 32 bf16
    char* base = (char*)lds + bs * 24576;
    gld16(sA0  + kb, base +            dofs);
    gld16(sA1  + kb, base +  4096 +    dofs);
    gld16(sB10 + kb, base +  8192 +    dofs);
    gld16(sB11 + kb, base + 12288 +    dofs);
    gld16(sB30 + kb, base + 16384 +    dofs);
    gld16(sB31 + kb, base + 20480 +    dofs);
  };

  const int chsw = ((lane >> 4) ^ ((lane >> 1) & 3)) * 8;  // swizzled read chunk
  int aofs[4], b1ofs[4], b3ofs[4];
#pragma unroll
  for (int i = 0; i < 4; i++){
    int am = wr * 64 + i * 16 + (lane & 15);
    int bn = wc * 64 + i * 16 + (lane & 15);
    aofs[i]  = am * 32 + chsw;
    b1ofs[i] = 4096 + bn * 32 + chsw;
    b3ofs[i] = 8192 + bn * 32 + chsw;
  }

  f32x4 acch[4][4], accg[4][4];
#pragma unroll
  for (int i = 0; i < 4; i++)
#pragma unroll
    for (int j = 0; j < 4; j++){
      acch[i][j] = (f32x4){0.f,0.f,0.f,0.f};
      accg[i][j] = (f32x4){0.f,0.f,0.f,0.f};
    }

  STAGE(0, 0);
  __syncthreads();
#pragma unroll 2
  for (int kt = 0; kt + 1 < DIM / 32; ++kt){
    const int bs = kt & 1;
    STAGE(bs ^ 1, kt + 1);
    const unsigned short* L = lds + bs * 12288;
    short8 a[4], b1[4], b3[4];
#pragma unroll
    for (int i = 0; i < 4; i++){
      a[i]  = *(const short8*)(L + aofs[i]);
      b1[i] = *(const short8*)(L + b1ofs[i]);
      b3[i] = *(const short8*)(L + b3ofs[i]);
    }
#pragma unroll
    for (int mi = 0; mi < 4; mi++)
#pragma unroll
      for (int ni = 0; ni < 4; ni++){
        acch[mi][ni] = __builtin_amdgcn_mfma_f32_16x16x32_bf16(a[mi], b1[ni], acch[mi][ni], 0, 0, 0);
        accg[mi][ni] = __builtin_amdgcn_mfma_f32_16x16x32_bf16(a[mi], b3[ni], accg[mi][ni], 0, 0, 0);
      }
    __syncthreads();          // drains vmcnt(0) AFTER the MFMA cluster
  }
  {
    const int bs = (DIM / 32 - 1) & 1;
    const unsigned short* L = lds + bs * 12288;
    short8 a[4], b1[4], b3[4];
#pragma unroll
    for (int i = 0; i < 4; i++){
      a[i]  = *(const short8*)(L + aofs[i]);
      b1[i] = *(const short8*)(L + b1ofs[i]);
      b3[i] = *(const short8*)(L + b3ofs[i]);
    }
#pragma unroll
    for (int mi = 0; mi < 4; mi++)
#pragma unroll
      for (int ni = 0; ni < 4; ni++){
        acch[mi][ni] = __builtin_amdgcn_mfma_f32_16x16x32_bf16(a[mi], b1[ni], acch[mi][ni], 0, 0, 0);
        accg[mi][ni] = __builtin_amdgcn_mfma_f32_16x16x32_bf16(a[mi], b3[ni], accg[mi][ni], 0, 0, 0);
      }
  }

#pragma unroll
  for (int mi = 0; mi < 4; mi++)
#pragma unroll
    for (int r = 0; r < 4; r++){
      int row_local = wr * 64 + mi * 16 + ((lane >> 4) << 2) + r;
      if (row_local < rows_left){
        size_t pair = (size_t)(off + rbase + row_local);
        unsigned short* arow = abuf + pair * HID + ct * 128 + wc * 64 + (lane & 15);
#pragma unroll
        for (int ni = 0; ni < 4; ni++){
          float h = acch[mi][ni][r], g = accg[mi][ni][r];
          float sv = h / (1.f + __expf(-h));
          arow[ni * 16] = f2bf(sv * g);
        }
      }
    }
}

// ---------------- stage 2: eo = A @ W2, scaled atomic into d_out ------------
__global__ __launch_bounds__(256,2) void ffn2_kernel(
    const unsigned short* __restrict__ abuf,
    const unsigned short* __restrict__ w2t,
    float* __restrict__ dout,
    const int* __restrict__ counts, const int* __restrict__ offs,
    const int* __restrict__ tlist, const float* __restrict__ wlist)
{
  const int e = blockIdx.x, ct = blockIdx.y, rt = blockIdx.z;
  const int cnt = counts[e];
  const int rbase = rt * 128;
  if (rbase >= cnt) return;
  const int off = offs[e];
  const int rows_left = cnt - rbase;
  const int t = threadIdx.x;
  const int lane = t & 63, w = t >> 6;
  const int wr = w >> 1, wc = w & 1;

  // [2 buffers][A:4096 | B:4096 elems] = 32 KB total
  __shared__ __align__(16) unsigned short lds[2 * 8192];

  int ar0 = t >> 2, ar1 = 64 + (t >> 2);
  int psw = (t & 3) ^ ((t >> 3) & 3);
  int ra0 = ar0 < rows_left ? ar0 : rows_left - 1;
  int ra1 = ar1 < rows_left ? ar1 : rows_left - 1;
  const char* sA0 = (const char*)abuf + ((size_t)(off + rbase + ra0) * HID) * 2 + psw * 16;
  const char* sA1 = (const char*)abuf + ((size_t)(off + rbase + ra1) * HID) * 2 + psw * 16;
  const char* sB0 = (const char*)w2t + (((size_t)e * ODIM + ct * 128 + ar0) * HID) * 2 + psw * 16;
  const char* sB1 = (const char*)w2t + (((size_t)e * ODIM + ct * 128 + ar1) * HID) * 2 + psw * 16;
  const int dofs = w * 1024;

  auto STAGE = [&](int bs, int kt){
    int kb = kt << 6;
    char* base = (char*)lds + bs * 16384;
    gld16(sA0 + kb, base +           dofs);
    gld16(sA1 + kb, base +  4096 +   dofs);
    gld16(sB0 + kb, base +  8192 +   dofs);
    gld16(sB1 + kb, base + 12288 +   dofs);
  };

  const int chsw = ((lane >> 4) ^ ((lane >> 1) & 3)) * 8;
  int aofs[4], bofs[4];
#pragma unroll
  for (int i = 0; i < 4; i++){
    int am = wr * 64 + i * 16 + (lane & 15);
    int bn = wc * 64 + i * 16 + (lane & 15);
    aofs[i] = am * 32 + chsw;
    bofs[i] = 4096 + bn * 32 + chsw;
  }

  f32x4 acc[4][4];
#pragma unroll
  for (int i = 0; i < 4; i++)
#pragma unroll
    for (int j = 0; j < 4; j++) acc[i][j] = (f32x4){0.f,0.f,0.f,0.f};

  STAGE(0, 0);
  __syncthreads();
#pragma unroll 2
  for (int kt = 0; kt + 1 < HID / 32; ++kt){
    const int bs = kt & 1;
    STAGE(bs ^ 1, kt + 1);
    const unsigned short* L = lds + bs * 8192;
    short8 a[4], b[4];
#pragma unroll
    for (int i = 0; i < 4; i++){
      a[i] = *(const short8*)(L + aofs[i]);
      b[i] = *(const short8*)(L + bofs[i]);
    }
#pragma unroll
    for (int mi = 0; mi < 4; mi++)
#pragma unroll
      for (int ni = 0; ni < 4; ni++)
        acc[mi][ni] = __builtin_amdgcn_mfma_f32_16x16x32_bf16(a[mi], b[ni], acc[mi][ni], 0, 0, 0);
    __syncthreads();
  }
  {
    const int bs = (HID / 32 - 1) & 1;
    const unsigned short* L = lds + bs * 8192;
    short8 a[4], b[4];
#pragma unroll
    for (int i = 0; i < 4; i++){
      a[i] = *(const short8*)(L + aofs[i]);
      b[i] = *(const short8*)(L + bofs[i]);
    }
#pragma unroll
    for (int mi = 0; mi < 4; mi++)
#pragma unroll
      for (int ni = 0; ni < 4; ni++)
        acc[mi][ni] = __builtin_amdgcn_mfma_f32_16x16x32_bf16(a[mi], b[ni], acc[mi][ni], 0, 0, 0);
  }

#pragma unroll
  for (int mi = 0; mi < 4; mi++)
#pragma unroll
    for (int r = 0; r < 4; r++){
      int row_local = wr * 64 + mi * 16 + ((lane >> 4) << 2) + r;
      if (row_local < rows_left){
        int pair = off + rbase + row_local;
        int token = tlist[pair];
        float p   = wlist[pair];
        float* orow = dout + (size_t)token * ODIM + ct * 128 + wc * 64 + (lane & 15);
#pragma unroll
        for (int ni = 0; ni < 4; ni++)
          atomicAdd(orow + ni * 16, p * acc[mi][ni][r]);
      }
    }
}

extern "C" void kernel_launch(void* const* d_in, const int* in_sizes, int n_in,
                              void* d_out, int out_size, void* d_ws, size_t ws_size,
                              hipStream_t stream)
{
  const float* x  = (const float*)d_in[0];
  const float* rw = (const float*)d_in[1];
  const float* rb = (const float*)d_in[2];
  const float* W1 = (const float*)d_in[3];
  const float* W3 = (const float*)d_in[4];
  const float* W2 = (const float*)d_in[5];

  char* ws = (char*)d_ws;
  const size_t off_ctrl = 0;                                   // counts[8] @0, offs[9] @64B
  const size_t off_toke = 256;
  const size_t off_tokw = off_toke + (size_t)TTOK * 8;
  const size_t off_tl   = off_tokw + (size_t)TTOK * 8;
  const size_t off_wl   = off_tl   + (size_t)2 * TTOK * 4;
  const size_t off_xbf  = off_wl   + (size_t)2 * TTOK * 4;
  const size_t off_w1t  = off_xbf  + (size_t)TTOK * DIM * 2;
  const size_t off_w3t  = off_w1t  + (size_t)NE * HID * DIM * 2;
  const size_t off_w2t  = off_w3t  + (size_t)NE * HID * DIM * 2;
  const size_t off_ab   = off_w2t  + (size_t)NE * ODIM * HID * 2;
  const size_t need     = off_ab   + (size_t)2 * TTOK * HID * 2;
  if (ws_size < need) return;  // workspace too small: leave output poisoned (visible failure)

  int* counts = (int*)(ws + off_ctrl);
  int* offs   = (int*)(ws + off_ctrl + 64);
  int2*   toke = (int2*)  (ws + off_toke);
  float2* tokw = (float2*)(ws + off_tokw);
  int*    tl   = (int*)   (ws + off_tl);
  float*  wl   = (float*) (ws + off_wl);
  unsigned short* xbf = (unsigned short*)(ws + off_xbf);
  unsigned short* w1t = (unsigned short*)(ws + off_w1t);
  unsigned short* w3t = (unsigned short*)(ws + off_w3t);
  unsigned short* w2t = (unsigned short*)(ws + off_w2t);
  unsigned short* ab  = (unsigned short*)(ws + off_ab);

  hipMemsetAsync(d_out, 0, (size_t)out_size * sizeof(float), stream);

  router_kernel<<<TTOK / 4, 256, 0, stream>>>(x, rw, rb, xbf, toke, tokw);
  plan_kernel<<<NE, 256, 0, stream>>>(toke, tokw, counts, offs, tl, wl);

  transpose_cvt<<<dim3(HID / 64, DIM / 128, NE), 256, 0, stream>>>(W1, w1t, DIM, HID);
  transpose_cvt<<<dim3(HID / 64, DIM / 128, NE), 256, 0, stream>>>(W3, w3t, DIM, HID);
  transpose_cvt<<<dim3(ODIM / 64, HID / 128, NE), 256, 0, stream>>>(W2, w2t, HID, ODIM);

  ffn1_kernel<<<dim3(NE, HID / 128, 32), 256, 0, stream>>>(xbf, w1t, w3t, ab, counts, offs, tl);
  ffn2_kernel<<<dim3(NE, ODIM / 128, 32), 256, 0, stream>>>(ab, w2t, (float*)d_out, counts, offs, tl, wl);
}